// Round 9
// baseline (589.571 us; speedup 1.0000x reference)
//
#include <hip/hip_runtime.h>
#include <stdint.h>

// Inputs/outputs fp32; internal compute bf16 MFMA + fp32 accumulate.
// B=4 S=2048 D=1024 H=16 DH=64 F=4096; M = B*S = 8192.

typedef short bf16x8 __attribute__((ext_vector_type(8)));
typedef unsigned short u16x8 __attribute__((ext_vector_type(8)));
typedef float f32x4 __attribute__((ext_vector_type(4)));
typedef unsigned int u32x2 __attribute__((ext_vector_type(2)));

#define MFMA16(a, b, c) __builtin_amdgcn_mfma_f32_16x16x32_bf16((a), (b), (c), 0, 0, 0)

// 0.125 (1/sqrt(64)) / ln(2): folded into Q so softmax runs in exp2 domain.
#define QSCALE 0.1803368801111204f

__device__ __forceinline__ float b2f(unsigned short u) {
    union { unsigned u32; float f; } x;
    x.u32 = ((unsigned)u) << 16;
    return x.f;
}
__device__ __forceinline__ unsigned short f2b(float f) {
    union { float f; unsigned u; } x;
    x.f = f;
    unsigned r = x.u + 0x7fff + ((x.u >> 16) & 1);  // RNE
    return (unsigned short)(r >> 16);
}

// async 16B global -> LDS (wave-uniform LDS base + lane*16 dest semantics)
__device__ __forceinline__ void gl16(const unsigned short* g, unsigned short* l) {
    __builtin_amdgcn_global_load_lds(
        (__attribute__((address_space(1))) unsigned int*)(unsigned long)g,
        (__attribute__((address_space(3))) unsigned int*)l, 16, 0, 0);
}

// ---------------------------------------------------------------------------
// fp32 -> bf16 bulk convert (8 elems/thread)
// ---------------------------------------------------------------------------
__global__ __launch_bounds__(256) void f2b_bulk(const float* __restrict__ in,
                                                unsigned short* __restrict__ out) {
    const long i = ((long)blockIdx.x * 256 + threadIdx.x) * 8;
    float4 a = *(const float4*)&in[i];
    float4 b = *(const float4*)&in[i + 4];
    u16x8 u;
    u[0] = f2b(a.x); u[1] = f2b(a.y); u[2] = f2b(a.z); u[3] = f2b(a.w);
    u[4] = f2b(b.x); u[5] = f2b(b.y); u[6] = f2b(b.z); u[7] = f2b(b.w);
    *(u16x8*)&out[i] = u;
}

// ---------------------------------------------------------------------------
// Tiled transpose fp32 -> bf16: out[(row0+batch*C+c)*out_ld + r] = in[b][r][c]
// ---------------------------------------------------------------------------
__global__ void transpose_f2b(const float* __restrict__ in,
                              unsigned short* __restrict__ out,
                              int R, int C, long in_batch_stride,
                              int out_row0, int out_ld) {
    __shared__ float tile[32][33];
    const int batch = blockIdx.z;
    const float* src = in + (long)batch * in_batch_stride;
    const int c0 = blockIdx.x * 32, r0 = blockIdx.y * 32;
    const int tx = threadIdx.x, ty = threadIdx.y;  // (32, 8)
#pragma unroll
    for (int i = 0; i < 32; i += 8)
        tile[ty + i][tx] = src[(long)(r0 + ty + i) * C + c0 + tx];
    __syncthreads();
#pragma unroll
    for (int i = 0; i < 32; i += 8)
        out[(long)(out_row0 + batch * C + c0 + ty + i) * out_ld + r0 + tx] =
            f2b(tile[tx][ty + i]);
}

// ---------------------------------------------------------------------------
// V^T builder: vt[(bh*64 + e)*2048 + s] = qkv[(b*2048+s)*3072 + 2048 + h*64 + e]
// ---------------------------------------------------------------------------
__global__ void transpose_v(const unsigned short* __restrict__ qkv,
                            unsigned short* __restrict__ vt) {
    __shared__ unsigned short tile[32][33];
    const int bh = blockIdx.z;
    const int b = bh >> 4, h = bh & 15;
    const int s0 = blockIdx.x * 32, e0 = blockIdx.y * 32;
    const int tx = threadIdx.x, ty = threadIdx.y;  // (32, 8)
    const unsigned short* src = qkv + ((long)b * 2048) * 3072 + 2048 + h * 64;
#pragma unroll
    for (int i = 0; i < 32; i += 8)
        tile[ty + i][tx] = src[(long)(s0 + ty + i) * 3072 + e0 + tx];
    __syncthreads();
    unsigned short* dst = vt + ((long)bh * 64) * 2048;
#pragma unroll
    for (int i = 0; i < 32; i += 8)
        dst[(long)(e0 + ty + i) * 2048 + s0 + tx] = tile[tx][ty + i];
}

__global__ void concat_bias(const float* __restrict__ bq,
                            const float* __restrict__ bk,
                            const float* __restrict__ bv,
                            float* __restrict__ out) {
    int n = blockIdx.x * 256 + threadIdx.x;  // 0..3071
    out[n] = (n < 1024) ? bq[n] : (n < 2048) ? bk[n - 1024] : bv[n - 2048];
}

__device__ __forceinline__ float to_f(float v) { return v; }
__device__ __forceinline__ float to_f(unsigned short v) { return b2f(v); }

// ---------------------------------------------------------------------------
// gemm256: r7 kernel, verbatim (verified correct). Used where the 256x256
// grid fills the GPU exactly (FF1: 512 blocks = 2 rounds). 2 fat phases per
// K-32 step, 4-slot ring, counted vmcnt(8), both-sides chunk swizzle.
// ---------------------------------------------------------------------------
template <typename RT>
__global__ __launch_bounds__(512, 2) void gemm256(
    const unsigned short* __restrict__ A, const unsigned short* __restrict__ Bt,
    unsigned short* __restrict__ C, const float* __restrict__ bias,
    const RT* __restrict__ resid, int M, int N, int K, int op) {
    __shared__ __align__(16) unsigned short As[4][256 * 32];  // 64 KB
    __shared__ __align__(16) unsigned short Bs[4][256 * 32];  // 64 KB
    const int tid = threadIdx.x;
    const int lane = tid & 63;
    const int wave = tid >> 6;
    const int quad = lane >> 4, lr = lane & 15;
    const int wr = wave >> 2, wc = wave & 3;

    const int nx = gridDim.x;
    const int nwg = nx * gridDim.y;
    const int orig = blockIdx.y * nx + blockIdx.x;
    const int wg = (orig & 7) * (nwg >> 3) + (orig >> 3);  // nwg % 8 == 0
    const long n0 = (long)(wg % nx) * 256;
    const long m0 = (long)(wg / nx) * 256;

    f32x4 acc[8][4] = {};

    const int trow = tid >> 2;
    const int tch = ((tid & 3) ^ ((tid >> 3) & 3)) * 8;
    const unsigned short* gA0 = A + (m0 + trow) * (long)K + tch;
    const unsigned short* gA1 = A + (m0 + 128 + trow) * (long)K + tch;
    const unsigned short* gB0 = Bt + (n0 + trow) * (long)K + tch;
    const unsigned short* gB1 = Bt + (n0 + 128 + trow) * (long)K + tch;
    unsigned short* const dA = &As[0][0] + tid * 8;
    unsigned short* const dB = &Bs[0][0] + tid * 8;

    int aoff[8], boff[4];
#pragma unroll
    for (int mi = 0; mi < 8; mi++) {
        const int r = wr * 128 + mi * 16 + lr;
        aoff[mi] = r * 32 + (quad ^ ((r >> 1) & 3)) * 8;
    }
#pragma unroll
    for (int ni = 0; ni < 4; ni++) {
        const int r = wc * 64 + ni * 16 + lr;
        boff[ni] = r * 32 + (quad ^ ((r >> 1) & 3)) * 8;
    }

#define STAGE_A(si)                                                   \
    {                                                                 \
        gl16(gA0 + (long)(si) * 32, dA + ((si) & 3) * 8192);          \
        gl16(gA1 + (long)(si) * 32, dA + ((si) & 3) * 8192 + 4096);   \
    }
#define STAGE_B(si)                                                   \
    {                                                                 \
        gl16(gB0 + (long)(si) * 32, dB + ((si) & 3) * 8192);          \
        gl16(gB1 + (long)(si) * 32, dB + ((si) & 3) * 8192 + 4096);   \
    }

    const int S = K >> 5;
    for (int s = 0; s < 3; s++) {
        STAGE_A(s);
        STAGE_B(s);
    }
    asm volatile("s_waitcnt vmcnt(8)" ::: "memory");
    __builtin_amdgcn_s_barrier();

    for (int s = 0; s < S; ++s) {
        const int slot = s & 3;
        const unsigned short* as_ = &As[slot][0];
        const unsigned short* bs_ = &Bs[slot][0];
        const bool st = (s + 3) < S;
        bf16x8 af[8], bf[4];
#pragma unroll
        for (int mi = 0; mi < 8; mi++) af[mi] = *(const bf16x8*)&as_[aoff[mi]];
        bf[0] = *(const bf16x8*)&bs_[boff[0]];
        bf[1] = *(const bf16x8*)&bs_[boff[1]];
        if (st) STAGE_A(s + 3);
        __builtin_amdgcn_s_barrier();
        asm volatile("s_waitcnt lgkmcnt(0)" ::: "memory");
        __builtin_amdgcn_sched_barrier(0);
        __builtin_amdgcn_s_setprio(1);
#pragma unroll
        for (int mi = 0; mi < 8; mi++) {
            acc[mi][0] = MFMA16(af[mi], bf[0], acc[mi][0]);
            acc[mi][1] = MFMA16(af[mi], bf[1], acc[mi][1]);
        }
        __builtin_amdgcn_s_setprio(0);
        __builtin_amdgcn_s_barrier();
        __builtin_amdgcn_sched_barrier(0);
        bf[2] = *(const bf16x8*)&bs_[boff[2]];
        bf[3] = *(const bf16x8*)&bs_[boff[3]];
        if (st) STAGE_B(s + 3);
        __builtin_amdgcn_s_barrier();
        asm volatile("s_waitcnt lgkmcnt(0)" ::: "memory");
        __builtin_amdgcn_sched_barrier(0);
        __builtin_amdgcn_s_setprio(1);
#pragma unroll
        for (int mi = 0; mi < 8; mi++) {
            acc[mi][2] = MFMA16(af[mi], bf[2], acc[mi][2]);
            acc[mi][3] = MFMA16(af[mi], bf[3], acc[mi][3]);
        }
        __builtin_amdgcn_s_setprio(0);
        if (s + 3 < S) {
            asm volatile("s_waitcnt vmcnt(8)" ::: "memory");
        } else if (s + 2 < S) {
            asm volatile("s_waitcnt vmcnt(4)" ::: "memory");
        } else {
            asm volatile("s_waitcnt vmcnt(0)" ::: "memory");
        }
        __builtin_amdgcn_s_barrier();
        __builtin_amdgcn_sched_barrier(0);
    }
#undef STAGE_A
#undef STAGE_B

#pragma unroll
    for (int ni = 0; ni < 4; ni++) {
        const long col = n0 + wc * 64 + ni * 16 + lr;
        const float bv = bias ? bias[col] : 0.0f;
        const float cscale = (op == 2 && col < 1024) ? QSCALE : 1.0f;
#pragma unroll
        for (int mi = 0; mi < 8; mi++) {
#pragma unroll
            for (int r = 0; r < 4; r++) {
                const long row = m0 + wr * 128 + mi * 16 + quad * 4 + r;
                float v = (acc[mi][ni][r] + bv) * cscale;
                if (resid) v += to_f(resid[row * (long)N + col]);
                if (op == 1) v = fmaxf(v, 0.0f);
                C[row * (long)N + col] = f2b(v);
            }
        }
    }
}

// ---------------------------------------------------------------------------
// gemmK64: full-GPU-grid variant for N<=3072 gemms (r8, verbatim; verified).
// BM=256, BN=128, BK=64, 3-slot ring (144 KB), counted vmcnt(6).
// ---------------------------------------------------------------------------
template <int TAG, typename RT>
__global__ __launch_bounds__(512, 2) void gemmK64(
    const unsigned short* __restrict__ A, const unsigned short* __restrict__ Bt,
    unsigned short* __restrict__ C, const float* __restrict__ bias,
    const RT* __restrict__ resid, int M, int N, int K, int op) {
    __shared__ __align__(16) unsigned short As[3][256 * 64];  // 96 KB
    __shared__ __align__(16) unsigned short Bs[3][128 * 64];  // 48 KB
    const int tid = threadIdx.x;
    const int lane = tid & 63;
    const int wave = tid >> 6;
    const int quad = lane >> 4, lr = lane & 15;
    const int wr = wave >> 1, wc = wave & 1;  // 4 x 2 wave grid

    const int nx = gridDim.x;
    const int nwg = nx * gridDim.y;
    const int orig = blockIdx.y * nx + blockIdx.x;
    const int wg = (orig & 7) * (nwg >> 3) + (orig >> 3);  // nwg % 8 == 0
    const long n0 = (long)(wg % nx) * 128;
    const long m0 = (long)(wg / nx) * 256;

    f32x4 acc[4][4] = {};

    const int trow = tid >> 3;  // 0..63
    const int tch = ((tid & 7) ^ ((tid >> 4) & 7)) * 8;
    const unsigned short* gA = A + (m0 + trow) * (long)K + tch;
    const unsigned short* gB = Bt + (n0 + trow) * (long)K + tch;
    const long rs64 = 64 * (long)K;  // 64-row stride
    unsigned short* const dA = &As[0][0] + tid * 8;
    unsigned short* const dB = &Bs[0][0] + tid * 8;

    int aoff[2][4], boff[2][4];
#pragma unroll
    for (int kc = 0; kc < 2; kc++) {
#pragma unroll
        for (int mi = 0; mi < 4; mi++) {
            const int r = wr * 64 + mi * 16 + lr;
            aoff[kc][mi] = r * 64 + (((kc << 2) | quad) ^ ((r >> 1) & 7)) * 8;
        }
#pragma unroll
        for (int ni = 0; ni < 4; ni++) {
            const int r = wc * 64 + ni * 16 + lr;
            boff[kc][ni] = r * 64 + (((kc << 2) | quad) ^ ((r >> 1) & 7)) * 8;
        }
    }

#define KSTAGE_H1(si)                                                   \
    {                                                                   \
        const long _kk = (long)(si) * 64;                               \
        const int _sl = (si) % 3;                                       \
        gl16(gA + _kk, dA + _sl * 16384);                               \
        gl16(gA + rs64 + _kk, dA + _sl * 16384 + 4096);                 \
        gl16(gB + _kk, dB + _sl * 8192);                                \
    }
#define KSTAGE_H2(si)                                                   \
    {                                                                   \
        const long _kk = (long)(si) * 64;                               \
        const int _sl = (si) % 3;                                       \
        gl16(gA + 2 * rs64 + _kk, dA + _sl * 16384 + 8192);             \
        gl16(gA + 3 * rs64 + _kk, dA + _sl * 16384 + 12288);            \
        gl16(gB + rs64 + _kk, dB + _sl * 8192 + 4096);                  \
    }

    const int S = K >> 6;  // K-steps of 64
    KSTAGE_H1(0);
    KSTAGE_H2(0);
    KSTAGE_H1(1);
    KSTAGE_H2(1);
    asm volatile("s_waitcnt vmcnt(6)" ::: "memory");  // slot 0 landed
    __builtin_amdgcn_s_barrier();

    for (int s = 0; s < S; ++s) {
        const int sl = s % 3;
        const unsigned short* as_ = &As[sl][0];
        const unsigned short* bs_ = &Bs[sl][0];
        const bool st = (s + 2) < S;
        bf16x8 a0[4], b0[4], a1[4], b1[4];
        // ---- phase 1: kc = 0
#pragma unroll
        for (int mi = 0; mi < 4; mi++) a0[mi] = *(const bf16x8*)&as_[aoff[0][mi]];
#pragma unroll
        for (int ni = 0; ni < 4; ni++) b0[ni] = *(const bf16x8*)&bs_[boff[0][ni]];
        if (st) KSTAGE_H1(s + 2);
        __builtin_amdgcn_s_barrier();
        asm volatile("s_waitcnt lgkmcnt(0)" ::: "memory");
        __builtin_amdgcn_sched_barrier(0);
        __builtin_amdgcn_s_setprio(1);
#pragma unroll
        for (int mi = 0; mi < 4; mi++)
#pragma unroll
            for (int ni = 0; ni < 4; ni++)
                acc[mi][ni] = MFMA16(a0[mi], b0[ni], acc[mi][ni]);
        __builtin_amdgcn_s_setprio(0);
        __builtin_amdgcn_s_barrier();
        __builtin_amdgcn_sched_barrier(0);
        // ---- phase 2: kc = 1
#pragma unroll
        for (int mi = 0; mi < 4; mi++) a1[mi] = *(const bf16x8*)&as_[aoff[1][mi]];
#pragma unroll
        for (int ni = 0; ni < 4; ni++) b1[ni] = *(const bf16x8*)&bs_[boff[1][ni]];
        if (st) KSTAGE_H2(s + 2);
        __builtin_amdgcn_s_barrier();
        asm volatile("s_waitcnt lgkmcnt(0)" ::: "memory");
        __builtin_amdgcn_sched_barrier(0);
        __builtin_amdgcn_s_setprio(1);
#pragma unroll
        for (int mi = 0; mi < 4; mi++)
#pragma unroll
            for (int ni = 0; ni < 4; ni++)
                acc[mi][ni] = MFMA16(a1[mi], b1[ni], acc[mi][ni]);
        __builtin_amdgcn_s_setprio(0);
        if (st) {
            asm volatile("s_waitcnt vmcnt(6)" ::: "memory");
        } else {
            asm volatile("s_waitcnt vmcnt(0)" ::: "memory");
        }
        __builtin_amdgcn_s_barrier();
        __builtin_amdgcn_sched_barrier(0);
    }
#undef KSTAGE_H1
#undef KSTAGE_H2

#pragma unroll
    for (int ni = 0; ni < 4; ni++) {
        const long col = n0 + wc * 64 + ni * 16 + lr;
        const float bv = bias ? bias[col] : 0.0f;
        const float cscale = (op == 2 && col < 1024) ? QSCALE : 1.0f;
#pragma unroll
        for (int mi = 0; mi < 4; mi++) {
#pragma unroll
            for (int r = 0; r < 4; r++) {
                const long row = m0 + wr * 64 + mi * 16 + quad * 4 + r;
                float v = (acc[mi][ni][r] + bv) * cscale;
                if (resid) v += to_f(resid[row * (long)N + col]);
                if (op == 1) v = fmaxf(v, 0.0f);
                C[row * (long)N + col] = f2b(v);
            }
        }
    }
}

// ---------------------------------------------------------------------------
// Flash attention v9: v7 + counted-vmcnt 3-slot ring (the gemmK64 trick).
// v7's per-iter __syncthreads() implicitly drained vmcnt to 0 -- a serial
// ~500-900 cyc HBM-latency stall every one of 32 iterations (compute/iter is
// only ~375 cyc; measured 70% idle). v9: Klds/Vlds are 3-slot rings (48 KB,
// 3 blocks/CU -- matches the measured ~37% effective occupancy, so the cap
// is ~free); stage tile kt+2 at the top of iter kt; end-of-iter wait is
// vmcnt(4) (certifies tile kt+1; tile kt+2's 4 loads fly across the
// barrier) + raw s_barrier. Tail: vmcnt(0) at kt=30; no barrier after 31.
// Race audit: stage(kt+2) writes slot (kt+2)%3 == (kt-1)%3, whose readers
// (iter kt-1) consumed all ds_reads before the end-of-(kt-1) barrier that
// every wave crossed before any wave issues this stage. ds_read->MFMA
// ordering is compiler-lgkmcnt-handled within the iteration. All branches
// uniform in kt -> no barrier divergence.
// ---------------------------------------------------------------------------
__global__ __launch_bounds__(256, 3) void attn_kernel(
    const unsigned short* __restrict__ qkv, const unsigned short* __restrict__ vt,
    unsigned short* __restrict__ o) {
    __shared__ __align__(16) unsigned short Klds[3][64 * 64];  // 24 KB
    __shared__ __align__(16) unsigned short Vlds[3][64 * 64];  // 24 KB
    // Block swizzle: all 32 q-tiles of one (b,h) share l%8 -> same XCD.
    const int l = blockIdx.x;
    const int bh = ((l >> 8) << 3) | (l & 7);
    const int qt = (l >> 3) & 31;
    const int b = bh >> 4, h = bh & 15;
    const int tid = threadIdx.x;
    const int wave = tid >> 6, lane = tid & 63;
    const int quad = lane >> 4, lr = lane & 15;
    const long rowbase = (long)b * 2048;
    const int qb = qt * 64 + wave * 16;

    // Q fragments (B operand; n = query = lr), register-resident
    bf16x8 q0, q1;
    {
        const unsigned short* qrow = qkv + (rowbase + qb + lr) * 3072 + h * 64;
        q0 = *(const bf16x8*)&qrow[quad * 8];
        q1 = *(const bf16x8*)&qrow[32 + quad * 8];
    }

    // all-ones bf16 A-fragment for the denominator MFMA
    bf16x8 ones;
#pragma unroll
    for (int i = 0; i < 8; i++) ones[i] = (short)0x3F80;

    // Staging: wave w stages rows [w*16, w*16+16) of the K and V tiles via
    // 2 gl16 each. Lane: row = base + (lane>>3), dst chunk = lane&7,
    // src chunk = (lane&7) ^ (row&7)  [row&7 == lane>>3 here].
    const int srow = lane >> 3;
    const int sxc = (lane & 7) ^ srow;
    const unsigned short* kp =
        qkv + (rowbase + wave * 16 + srow) * 3072 + 1024 + h * 64 + sxc * 8;
    const unsigned short* vp =
        vt + ((long)bh * 64 + wave * 16 + srow) * 2048 + sxc * 8;
    const long KADV = 64L * 3072;  // next key-tile (rows)
    unsigned short* const kd0 = &Klds[0][wave * 16 * 64];
    unsigned short* const vd0 = &Vlds[0][wave * 16 * 64];

    // kp/vp always point at the NEXT tile to stage.
#define STAGE(sl)                                                     \
    {                                                                 \
        gl16(kp, kd0 + (sl)*4096);                                    \
        gl16(kp + 8 * 3072, kd0 + (sl)*4096 + 8 * 64);                \
        gl16(vp, vd0 + (sl)*4096);                                    \
        gl16(vp + 8 * 2048, vd0 + (sl)*4096 + 8 * 64);                \
        kp += KADV;                                                   \
        vp += 64;                                                     \
    }

    f32x4 oacc[4] = {};
    f32x4 dacc = {};  // denominator accumulator (all rows identical)

    // swizzled chunk offsets for A-operand reads (row&7 == lr&7)
    const int x7 = lr & 7;
    const int c00 = (quad ^ x7) * 8;        // kc=0
    const int c01 = ((4 | quad) ^ x7) * 8;  // kc=1

    STAGE(0);
    STAGE(1);
    asm volatile("s_waitcnt vmcnt(4)" ::: "memory");  // tile 0 landed
    __builtin_amdgcn_s_barrier();

    for (int kt = 0; kt < 32; kt++) {
        const int sl = kt % 3;
        if (kt < 30) STAGE((kt + 2) % 3);
        // S^T = K·Q^T  (A = K tile rows, k-dim = dh)
        const unsigned short* kb = &Klds[sl][0];
        f32x4 s4[4];
#pragma unroll
        for (int nt = 0; nt < 4; nt++) {
            const unsigned short* krow = kb + (nt * 16 + lr) * 64;
            bf16x8 k0 = *(const bf16x8*)&krow[c00];
            bf16x8 k1 = *(const bf16x8*)&krow[c01];
            f32x4 z = {};
            z = MFMA16(k0, q0, z);
            z = MFMA16(k1, q1, z);
            s4[nt] = z;
        }
        // p = exp2(s) unnormalized; pack pairs to bf16 (v_cvt_pk, RNE).
        unsigned pwv[4][2];
#pragma unroll
        for (int nt = 0; nt < 4; nt++) {
            float p0 = exp2f(s4[nt][0]);
            float p1 = exp2f(s4[nt][1]);
            float p2 = exp2f(s4[nt][2]);
            float p3 = exp2f(s4[nt][3]);
            asm("v_cvt_pk_bf16_f32 %0, %1, %2"
                : "=v"(pwv[nt][0]) : "v"(p0), "v"(p1));
            asm("v_cvt_pk_bf16_f32 %0, %1, %2"
                : "=v"(pwv[nt][1]) : "v"(p2), "v"(p3));
        }
        // In-register P^T quad redistribution (permlane swaps).
        unsigned pq[2][4];
#pragma unroll
        for (int kc = 0; kc < 2; kc++)
#pragma unroll
            for (int tl = 0; tl < 2; tl++) {
                u32x2 y = __builtin_amdgcn_permlane32_swap(
                    pwv[2 * kc][tl], pwv[2 * kc + 1][tl], false, false);
                u32x2 z = __builtin_amdgcn_permlane16_swap(y[0], y[1], false, false);
                pq[kc][tl] = z[0];
                pq[kc][2 + tl] = z[1];
            }

        // O^T += V^T·P^T + denominator row-sum on the matrix pipe.
        const unsigned short* vb = &Vlds[sl][0];
#pragma unroll
        for (int kc = 0; kc < 2; kc++) {
            union { unsigned u[4]; bf16x8 h; } pu;
            pu.u[0] = pq[kc][0]; pu.u[1] = pq[kc][1];
            pu.u[2] = pq[kc][2]; pu.u[3] = pq[kc][3];
            const int vc = kc ? c01 : c00;
            dacc = MFMA16(ones, pu.h, dacc);
#pragma unroll
            for (int nt = 0; nt < 4; nt++) {
                bf16x8 va = *(const bf16x8*)&vb[(nt * 16 + lr) * 64 + vc];
                oacc[nt] = MFMA16(va, pu.h, oacc[nt]);
            }
        }
        // Counted end-of-iter sync: certify tile kt+1; tile kt+2's 4 loads
        // stay in flight across the barrier. No barrier after the last iter.
        if (kt < 30) {
            asm volatile("s_waitcnt vmcnt(4)" ::: "memory");
            __builtin_amdgcn_s_barrier();
        } else if (kt == 30) {
            asm volatile("s_waitcnt vmcnt(0)" ::: "memory");
            __builtin_amdgcn_s_barrier();
        }
    }

    // dacc rows are identical: dacc[0] = full denominator for query lr.
    const float rinv = 1.0f / dacc[0];

    // O^T C-layout: (e = nt*16+quad*4+r, q = lr) -> packed ushort4 stores
    const long orow = rowbase + qb + lr;
#pragma unroll
    for (int nt = 0; nt < 4; nt++) {
        ushort4 ov = {f2b(oacc[nt][0] * rinv), f2b(oacc[nt][1] * rinv),
                      f2b(oacc[nt][2] * rinv), f2b(oacc[nt][3] * rinv)};
        *(ushort4*)&o[orow * 1024 + h * 64 + nt * 16 + quad * 4] = ov;
    }
#undef STAGE
}

// ---------------------------------------------------------------------------
// LayerNorm over last dim (1024), bf16 in, OT out, fp32 stats/params.
// ---------------------------------------------------------------------------
__device__ __forceinline__ void st4(float* p, float a, float b, float c, float d) {
    float4 v = {a, b, c, d};
    *(float4*)p = v;
}
__device__ __forceinline__ void st4(unsigned short* p, float a, float b, float c,
                                    float d) {
    ushort4 v = {f2b(a), f2b(b), f2b(c), f2b(d)};
    *(ushort4*)p = v;
}

template <typename OT>
__global__ __launch_bounds__(256) void ln_kernel(
    const unsigned short* __restrict__ in, const float* __restrict__ g,
    const float* __restrict__ b, OT* __restrict__ out) {
    __shared__ float red[4];
    const long row = blockIdx.x;
    const int tid = threadIdx.x;
    ushort4 u = *(const ushort4*)&in[row * 1024 + tid * 4];
    float v[4] = {b2f(u.x), b2f(u.y), b2f(u.z), b2f(u.w)};
    float s = v[0] + v[1] + v[2] + v[3];
#pragma unroll
    for (int off = 32; off > 0; off >>= 1) s += __shfl_down(s, off, 64);
    if ((tid & 63) == 0) red[tid >> 6] = s;
    __syncthreads();
    const float mu = (red[0] + red[1] + red[2] + red[3]) * (1.0f / 1024.0f);
    __syncthreads();
    float d[4], sq = 0.f;
#pragma unroll
    for (int i = 0; i < 4; i++) { d[i] = v[i] - mu; sq += d[i] * d[i]; }
#pragma unroll
    for (int off = 32; off > 0; off >>= 1) sq += __shfl_down(sq, off, 64);
    if ((tid & 63) == 0) red[tid >> 6] = sq;
    __syncthreads();
    const float var = (red[0] + red[1] + red[2] + red[3]) * (1.0f / 1024.0f);
    const float rs = rsqrtf(var + 1e-5f);
    float4 gu = *(const float4*)&g[tid * 4];
    float4 bu = *(const float4*)&b[tid * 4];
    st4(&out[row * 1024 + tid * 4], d[0] * rs * gu.x + bu.x,
        d[1] * rs * gu.y + bu.y, d[2] * rs * gu.z + bu.z,
        d[3] * rs * gu.w + bu.w);
}

// ---------------------------------------------------------------------------
extern "C" void kernel_launch(void* const* d_in, const int* in_sizes, int n_in,
                              void* d_out, int out_size, void* d_ws, size_t ws_size,
                              hipStream_t stream) {
    (void)in_sizes; (void)n_in; (void)out_size; (void)ws_size;
    const float* x   = (const float*)d_in[0];
    const float* wq  = (const float*)d_in[1];
    const float* bq  = (const float*)d_in[2];
    const float* wk  = (const float*)d_in[3];
    const float* bk  = (const float*)d_in[4];
    const float* wv  = (const float*)d_in[5];
    const float* bv  = (const float*)d_in[6];
    const float* wo  = (const float*)d_in[7];
    const float* bo  = (const float*)d_in[8];
    const float* g1  = (const float*)d_in[9];
    const float* be1 = (const float*)d_in[10];
    const float* w1  = (const float*)d_in[11];
    const float* b1  = (const float*)d_in[12];
    const float* w2  = (const float*)d_in[13];
    const float* b2  = (const float*)d_in[14];
    const float* g2  = (const float*)d_in[15];
    const float* be2 = (const float*)d_in[16];

    // Workspace (bf16 unless noted), high-water 153 MB.
    char* ws = (char*)d_ws;
    const size_t MB = 1024 * 1024;
    unsigned short* WT_QKV = (unsigned short*)(ws + 0);        // [3072,1024]
    unsigned short* WT_O   = (unsigned short*)(ws + 6 * MB);   // [1024,1024]
    unsigned short* WT_1   = (unsigned short*)(ws + 8 * MB);   // [4096,1024]
    unsigned short* WT_2   = (unsigned short*)(ws + 16 * MB);  // [1024,4096]
    float*          BQKV   = (float*)(ws + 24 * MB);           // [3072]
    unsigned short* XB     = (unsigned short*)(ws + 25 * MB);  // [8192,1024]
    unsigned short* QKV    = (unsigned short*)(ws + 41 * MB);  // [8192,3072]
    unsigned short* O      = (unsigned short*)(ws + 89 * MB);  // [8192,1024]
    unsigned short* R1     = (unsigned short*)(ws + 25 * MB);  // over dead XB
    unsigned short* Y      = (unsigned short*)(ws + 41 * MB);  // over dead QKV
    unsigned short* R2     = (unsigned short*)(ws + 57 * MB);  // over dead QKV
    unsigned short* Hb     = (unsigned short*)(ws + 73 * MB);  // [8192,4096]
    unsigned short* VT     = (unsigned short*)(ws + 137 * MB); // [64,64,2048]
    float*          OUT    = (float*)d_out;

    const dim3 tb(32, 8, 1);
    transpose_f2b<<<dim3(2, 32, 16), tb, 0, stream>>>(wq, WT_QKV, 1024, 64, 65536L, 0, 1024);
    transpose_f2b<<<dim3(2, 32, 16), tb, 0, stream>>>(wk, WT_QKV, 1024, 64, 65536L, 1024, 1024);
    transpose_f2b<<<dim3(2, 32, 16), tb, 0, stream>>>(wv, WT_QKV, 1024, 64, 65536L, 2048, 1024);
    transpose_f2b<<<dim3(32, 32, 1), tb, 0, stream>>>(wo, WT_O, 1024, 1024, 0L, 0, 1024);
    transpose_f2b<<<dim3(128, 32, 1), tb, 0, stream>>>(w1, WT_1, 1024, 4096, 0L, 0, 1024);
    transpose_f2b<<<dim3(32, 128, 1), tb, 0, stream>>>(w2, WT_2, 4096, 1024, 0L, 0, 4096);
    concat_bias<<<dim3(12), 256, 0, stream>>>(bq, bk, bv, BQKV);
    f2b_bulk<<<dim3(4096), 256, 0, stream>>>(x, XB);

    // QKV projection: BM=256 BN=128, grid 24x32 = 768 blocks (3 full rounds)
    gemmK64<0, unsigned short><<<dim3(24, 32), 512, 0, stream>>>(
        XB, WT_QKV, QKV, BQKV, (const unsigned short*)nullptr, 8192, 3072, 1024, 2);
    // V^T per head -> VT
    transpose_v<<<dim3(64, 2, 64), tb, 0, stream>>>(QKV, VT);
    // Flash attention -> O
    attn_kernel<<<dim3(2048), 256, 0, stream>>>(QKV, VT, O);
    // Out-proj + bo + residual x(fp32) -> R1: grid 8x32 = 256 (1 full round)
    gemmK64<1, float><<<dim3(8, 32), 512, 0, stream>>>(
        O, WT_O, R1, bo, x, 8192, 1024, 1024, 0);
    // LN1 -> Y
    ln_kernel<unsigned short><<<dim3(8192), 256, 0, stream>>>(R1, g1, be1, Y);
    // FF1 + b1 + ReLU -> Hb: 256x256 tiles, grid 16x32 = 512 (2 full rounds)
    gemm256<unsigned short><<<dim3(16, 32), 512, 0, stream>>>(
        Y, WT_1, Hb, b1, (const unsigned short*)nullptr, 8192, 4096, 1024, 1);
    // FF2 + b2 + residual Y -> R2: grid 8x32 = 256 (1 full round), K=4096
    gemmK64<2, unsigned short><<<dim3(8, 32), 512, 0, stream>>>(
        Hb, WT_2, R2, b2, Y, 8192, 1024, 4096, 0);
    // LN2 -> out (fp32)
    ln_kernel<float><<<dim3(8192), 256, 0, stream>>>(R2, g2, be2, OUT);
}

// Round 10
// 561.201 us; speedup vs baseline: 1.0506x; 1.0506x over previous
//
#include <hip/hip_runtime.h>
#include <stdint.h>

// Inputs/outputs fp32; internal compute bf16 MFMA + fp32 accumulate.
// B=4 S=2048 D=1024 H=16 DH=64 F=4096; M = B*S = 8192.

typedef short bf16x8 __attribute__((ext_vector_type(8)));
typedef unsigned short u16x8 __attribute__((ext_vector_type(8)));
typedef float f32x4 __attribute__((ext_vector_type(4)));
typedef unsigned int u32x2 __attribute__((ext_vector_type(2)));

#define MFMA16(a, b, c) __builtin_amdgcn_mfma_f32_16x16x32_bf16((a), (b), (c), 0, 0, 0)

// 0.125 (1/sqrt(64)) / ln(2): folded into Q so softmax runs in exp2 domain.
#define QSCALE 0.1803368801111204f

__device__ __forceinline__ float b2f(unsigned short u) {
    union { unsigned u32; float f; } x;
    x.u32 = ((unsigned)u) << 16;
    return x.f;
}
__device__ __forceinline__ unsigned short f2b(float f) {
    union { float f; unsigned u; } x;
    x.f = f;
    unsigned r = x.u + 0x7fff + ((x.u >> 16) & 1);  // RNE
    return (unsigned short)(r >> 16);
}

// async 16B global -> LDS (wave-uniform LDS base + lane*16 dest semantics)
__device__ __forceinline__ void gl16(const unsigned short* g, unsigned short* l) {
    __builtin_amdgcn_global_load_lds(
        (__attribute__((address_space(1))) unsigned int*)(unsigned long)g,
        (__attribute__((address_space(3))) unsigned int*)l, 16, 0, 0);
}

// ---------------------------------------------------------------------------
// prep_kernel: fuses the 8 independent preprocessing launches into ONE
// dispatch (launch-gap elimination): 3 QKV weight transposes, wo/w1/w2
// transposes, bias concat, x fp32->bf16 bulk convert. Task selected by
// blockIdx.x range (block-uniform branch -> barriers safe). Block = (32,8).
//   [    0, 1024)  wq  -> WT_QKV rows    0..1023   (per-head transpose)
//   [ 1024, 2048)  wk  -> WT_QKV rows 1024..2047
//   [ 2048, 3072)  wv  -> WT_QKV rows 2048..3071
//   [ 3072, 4096)  wo  -> WT_O   [1024,1024]
//   [ 4096, 8192)  w1  -> WT_1   [4096,1024]
//   [ 8192,12288)  w2  -> WT_2   [1024,4096]
//   [12288,12300)  concat bq|bk|bv -> BQKV (fp32)
//   [12300,16396)  x -> XB bf16 (8 elems/thread)
// ---------------------------------------------------------------------------
__global__ void prep_kernel(
    const float* __restrict__ wq, const float* __restrict__ wk,
    const float* __restrict__ wv, const float* __restrict__ wo,
    const float* __restrict__ w1, const float* __restrict__ w2,
    const float* __restrict__ bq, const float* __restrict__ bk,
    const float* __restrict__ bv, const float* __restrict__ x,
    unsigned short* __restrict__ WT_QKV, unsigned short* __restrict__ WT_O,
    unsigned short* __restrict__ WT_1, unsigned short* __restrict__ WT_2,
    float* __restrict__ BQKV, unsigned short* __restrict__ XB) {
    __shared__ float tile[32][33];
    const int f = blockIdx.x;
    const int tx = threadIdx.x, ty = threadIdx.y;  // (32, 8)

    if (f < 3072) {
        // per-head QKV weight transpose: head bz of [1024,64] -> 64 rows
        const int which = f >> 10;  // 0=q 1=k 2=v
        const int g = f & 1023;
        const float* w = (which == 0) ? wq : (which == 1) ? wk : wv;
        const int bx = g & 1, by = (g >> 1) & 31, bz = g >> 6;
        const float* src = w + (long)bz * 65536;
        const int c0 = bx * 32, r0 = by * 32;
#pragma unroll
        for (int i = 0; i < 32; i += 8)
            tile[ty + i][tx] = src[(long)(r0 + ty + i) * 64 + c0 + tx];
        __syncthreads();
        const int row0 = which * 1024 + bz * 64 + c0;
#pragma unroll
        for (int i = 0; i < 32; i += 8)
            WT_QKV[(long)(row0 + ty + i) * 1024 + r0 + tx] = f2b(tile[tx][ty + i]);
    } else if (f < 4096) {
        const int g = f - 3072;
        const int bx = g & 31, by = g >> 5;
        const int c0 = bx * 32, r0 = by * 32;
#pragma unroll
        for (int i = 0; i < 32; i += 8)
            tile[ty + i][tx] = wo[(long)(r0 + ty + i) * 1024 + c0 + tx];
        __syncthreads();
#pragma unroll
        for (int i = 0; i < 32; i += 8)
            WT_O[(long)(c0 + ty + i) * 1024 + r0 + tx] = f2b(tile[tx][ty + i]);
    } else if (f < 8192) {
        const int g = f - 4096;
        const int bx = g & 127, by = g >> 7;  // C=4096: 128 x-tiles
        const int c0 = bx * 32, r0 = by * 32;
#pragma unroll
        for (int i = 0; i < 32; i += 8)
            tile[ty + i][tx] = w1[(long)(r0 + ty + i) * 4096 + c0 + tx];
        __syncthreads();
#pragma unroll
        for (int i = 0; i < 32; i += 8)
            WT_1[(long)(c0 + ty + i) * 1024 + r0 + tx] = f2b(tile[tx][ty + i]);
    } else if (f < 12288) {
        const int g = f - 8192;
        const int bx = g & 31, by = g >> 5;  // R=4096: 128 y-tiles
        const int c0 = bx * 32, r0 = by * 32;
#pragma unroll
        for (int i = 0; i < 32; i += 8)
            tile[ty + i][tx] = w2[(long)(r0 + ty + i) * 1024 + c0 + tx];
        __syncthreads();
#pragma unroll
        for (int i = 0; i < 32; i += 8)
            WT_2[(long)(c0 + ty + i) * 4096 + r0 + tx] = f2b(tile[tx][ty + i]);
    } else if (f < 12300) {
        const int n = (f - 12288) * 256 + ty * 32 + tx;  // 0..3071
        BQKV[n] = (n < 1024) ? bq[n] : (n < 2048) ? bk[n - 1024] : bv[n - 2048];
    } else {
        const long i = ((long)(f - 12300) * 256 + ty * 32 + tx) * 8;
        float4 a = *(const float4*)&x[i];
        float4 b = *(const float4*)&x[i + 4];
        u16x8 u;
        u[0] = f2b(a.x); u[1] = f2b(a.y); u[2] = f2b(a.z); u[3] = f2b(a.w);
        u[4] = f2b(b.x); u[5] = f2b(b.y); u[6] = f2b(b.z); u[7] = f2b(b.w);
        *(u16x8*)&XB[i] = u;
    }
}

// ---------------------------------------------------------------------------
// V^T builder: vt[(bh*64 + e)*2048 + s] = qkv[(b*2048+s)*3072 + 2048 + h*64 + e]
// ---------------------------------------------------------------------------
__global__ void transpose_v(const unsigned short* __restrict__ qkv,
                            unsigned short* __restrict__ vt) {
    __shared__ unsigned short tile[32][33];
    const int bh = blockIdx.z;
    const int b = bh >> 4, h = bh & 15;
    const int s0 = blockIdx.x * 32, e0 = blockIdx.y * 32;
    const int tx = threadIdx.x, ty = threadIdx.y;  // (32, 8)
    const unsigned short* src = qkv + ((long)b * 2048) * 3072 + 2048 + h * 64;
#pragma unroll
    for (int i = 0; i < 32; i += 8)
        tile[ty + i][tx] = src[(long)(s0 + ty + i) * 3072 + e0 + tx];
    __syncthreads();
    unsigned short* dst = vt + ((long)bh * 64) * 2048;
#pragma unroll
    for (int i = 0; i < 32; i += 8)
        dst[(long)(e0 + ty + i) * 2048 + s0 + tx] = tile[tx][ty + i];
}

__device__ __forceinline__ float to_f(float v) { return v; }
__device__ __forceinline__ float to_f(unsigned short v) { return b2f(v); }

// ---------------------------------------------------------------------------
// gemm256: verified r7/r8 kernel. 256x256 tile, 2 fat phases per K-32 step,
// 4-slot ring, counted vmcnt(8), both-sides chunk swizzle. Used for FF1
// (512 blocks = 2 exact full-GPU rounds).
// ---------------------------------------------------------------------------
template <typename RT>
__global__ __launch_bounds__(512, 2) void gemm256(
    const unsigned short* __restrict__ A, const unsigned short* __restrict__ Bt,
    unsigned short* __restrict__ C, const float* __restrict__ bias,
    const RT* __restrict__ resid, int M, int N, int K, int op) {
    __shared__ __align__(16) unsigned short As[4][256 * 32];  // 64 KB
    __shared__ __align__(16) unsigned short Bs[4][256 * 32];  // 64 KB
    const int tid = threadIdx.x;
    const int lane = tid & 63;
    const int wave = tid >> 6;
    const int quad = lane >> 4, lr = lane & 15;
    const int wr = wave >> 2, wc = wave & 3;

    const int nx = gridDim.x;
    const int nwg = nx * gridDim.y;
    const int orig = blockIdx.y * nx + blockIdx.x;
    const int wg = (orig & 7) * (nwg >> 3) + (orig >> 3);  // nwg % 8 == 0
    const long n0 = (long)(wg % nx) * 256;
    const long m0 = (long)(wg / nx) * 256;

    f32x4 acc[8][4] = {};

    const int trow = tid >> 2;
    const int tch = ((tid & 3) ^ ((tid >> 3) & 3)) * 8;
    const unsigned short* gA0 = A + (m0 + trow) * (long)K + tch;
    const unsigned short* gA1 = A + (m0 + 128 + trow) * (long)K + tch;
    const unsigned short* gB0 = Bt + (n0 + trow) * (long)K + tch;
    const unsigned short* gB1 = Bt + (n0 + 128 + trow) * (long)K + tch;
    unsigned short* const dA = &As[0][0] + tid * 8;
    unsigned short* const dB = &Bs[0][0] + tid * 8;

    int aoff[8], boff[4];
#pragma unroll
    for (int mi = 0; mi < 8; mi++) {
        const int r = wr * 128 + mi * 16 + lr;
        aoff[mi] = r * 32 + (quad ^ ((r >> 1) & 3)) * 8;
    }
#pragma unroll
    for (int ni = 0; ni < 4; ni++) {
        const int r = wc * 64 + ni * 16 + lr;
        boff[ni] = r * 32 + (quad ^ ((r >> 1) & 3)) * 8;
    }

#define STAGE_A(si)                                                   \
    {                                                                 \
        gl16(gA0 + (long)(si) * 32, dA + ((si) & 3) * 8192);          \
        gl16(gA1 + (long)(si) * 32, dA + ((si) & 3) * 8192 + 4096);   \
    }
#define STAGE_B(si)                                                   \
    {                                                                 \
        gl16(gB0 + (long)(si) * 32, dB + ((si) & 3) * 8192);          \
        gl16(gB1 + (long)(si) * 32, dB + ((si) & 3) * 8192 + 4096);   \
    }

    const int S = K >> 5;
    for (int s = 0; s < 3; s++) {
        STAGE_A(s);
        STAGE_B(s);
    }
    asm volatile("s_waitcnt vmcnt(8)" ::: "memory");
    __builtin_amdgcn_s_barrier();

    for (int s = 0; s < S; ++s) {
        const int slot = s & 3;
        const unsigned short* as_ = &As[slot][0];
        const unsigned short* bs_ = &Bs[slot][0];
        const bool st = (s + 3) < S;
        bf16x8 af[8], bf[4];
#pragma unroll
        for (int mi = 0; mi < 8; mi++) af[mi] = *(const bf16x8*)&as_[aoff[mi]];
        bf[0] = *(const bf16x8*)&bs_[boff[0]];
        bf[1] = *(const bf16x8*)&bs_[boff[1]];
        if (st) STAGE_A(s + 3);
        __builtin_amdgcn_s_barrier();
        asm volatile("s_waitcnt lgkmcnt(0)" ::: "memory");
        __builtin_amdgcn_sched_barrier(0);
        __builtin_amdgcn_s_setprio(1);
#pragma unroll
        for (int mi = 0; mi < 8; mi++) {
            acc[mi][0] = MFMA16(af[mi], bf[0], acc[mi][0]);
            acc[mi][1] = MFMA16(af[mi], bf[1], acc[mi][1]);
        }
        __builtin_amdgcn_s_setprio(0);
        __builtin_amdgcn_s_barrier();
        __builtin_amdgcn_sched_barrier(0);
        bf[2] = *(const bf16x8*)&bs_[boff[2]];
        bf[3] = *(const bf16x8*)&bs_[boff[3]];
        if (st) STAGE_B(s + 3);
        __builtin_amdgcn_s_barrier();
        asm volatile("s_waitcnt lgkmcnt(0)" ::: "memory");
        __builtin_amdgcn_sched_barrier(0);
        __builtin_amdgcn_s_setprio(1);
#pragma unroll
        for (int mi = 0; mi < 8; mi++) {
            acc[mi][2] = MFMA16(af[mi], bf[2], acc[mi][2]);
            acc[mi][3] = MFMA16(af[mi], bf[3], acc[mi][3]);
        }
        __builtin_amdgcn_s_setprio(0);
        if (s + 3 < S) {
            asm volatile("s_waitcnt vmcnt(8)" ::: "memory");
        } else if (s + 2 < S) {
            asm volatile("s_waitcnt vmcnt(4)" ::: "memory");
        } else {
            asm volatile("s_waitcnt vmcnt(0)" ::: "memory");
        }
        __builtin_amdgcn_s_barrier();
        __builtin_amdgcn_sched_barrier(0);
    }
#undef STAGE_A
#undef STAGE_B

#pragma unroll
    for (int ni = 0; ni < 4; ni++) {
        const long col = n0 + wc * 64 + ni * 16 + lr;
        const float bv = bias ? bias[col] : 0.0f;
        const float cscale = (op == 2 && col < 1024) ? QSCALE : 1.0f;
#pragma unroll
        for (int mi = 0; mi < 8; mi++) {
#pragma unroll
            for (int r = 0; r < 4; r++) {
                const long row = m0 + wr * 128 + mi * 16 + quad * 4 + r;
                float v = (acc[mi][ni][r] + bv) * cscale;
                if (resid) v += to_f(resid[row * (long)N + col]);
                if (op == 1) v = fmaxf(v, 0.0f);
                C[row * (long)N + col] = f2b(v);
            }
        }
    }
}

// ---------------------------------------------------------------------------
// gemmK64: full-GPU-grid variant for N<=3072 gemms (r8, verbatim; verified).
// BM=256, BN=128, BK=64, 3-slot ring (144 KB), counted vmcnt(6).
// ---------------------------------------------------------------------------
template <int TAG, typename RT>
__global__ __launch_bounds__(512, 2) void gemmK64(
    const unsigned short* __restrict__ A, const unsigned short* __restrict__ Bt,
    unsigned short* __restrict__ C, const float* __restrict__ bias,
    const RT* __restrict__ resid, int M, int N, int K, int op) {
    __shared__ __align__(16) unsigned short As[3][256 * 64];  // 96 KB
    __shared__ __align__(16) unsigned short Bs[3][128 * 64];  // 48 KB
    const int tid = threadIdx.x;
    const int lane = tid & 63;
    const int wave = tid >> 6;
    const int quad = lane >> 4, lr = lane & 15;
    const int wr = wave >> 1, wc = wave & 1;  // 4 x 2 wave grid

    const int nx = gridDim.x;
    const int nwg = nx * gridDim.y;
    const int orig = blockIdx.y * nx + blockIdx.x;
    const int wg = (orig & 7) * (nwg >> 3) + (orig >> 3);  // nwg % 8 == 0
    const long n0 = (long)(wg % nx) * 128;
    const long m0 = (long)(wg / nx) * 256;

    f32x4 acc[4][4] = {};

    const int trow = tid >> 3;  // 0..63
    const int tch = ((tid & 7) ^ ((tid >> 4) & 7)) * 8;
    const unsigned short* gA = A + (m0 + trow) * (long)K + tch;
    const unsigned short* gB = Bt + (n0 + trow) * (long)K + tch;
    const long rs64 = 64 * (long)K;  // 64-row stride
    unsigned short* const dA = &As[0][0] + tid * 8;
    unsigned short* const dB = &Bs[0][0] + tid * 8;

    int aoff[2][4], boff[2][4];
#pragma unroll
    for (int kc = 0; kc < 2; kc++) {
#pragma unroll
        for (int mi = 0; mi < 4; mi++) {
            const int r = wr * 64 + mi * 16 + lr;
            aoff[kc][mi] = r * 64 + (((kc << 2) | quad) ^ ((r >> 1) & 7)) * 8;
        }
#pragma unroll
        for (int ni = 0; ni < 4; ni++) {
            const int r = wc * 64 + ni * 16 + lr;
            boff[kc][ni] = r * 64 + (((kc << 2) | quad) ^ ((r >> 1) & 7)) * 8;
        }
    }

#define KSTAGE_H1(si)                                                   \
    {                                                                   \
        const long _kk = (long)(si) * 64;                               \
        const int _sl = (si) % 3;                                       \
        gl16(gA + _kk, dA + _sl * 16384);                               \
        gl16(gA + rs64 + _kk, dA + _sl * 16384 + 4096);                 \
        gl16(gB + _kk, dB + _sl * 8192);                                \
    }
#define KSTAGE_H2(si)                                                   \
    {                                                                   \
        const long _kk = (long)(si) * 64;                               \
        const int _sl = (si) % 3;                                       \
        gl16(gA + 2 * rs64 + _kk, dA + _sl * 16384 + 8192);             \
        gl16(gA + 3 * rs64 + _kk, dA + _sl * 16384 + 12288);            \
        gl16(gB + rs64 + _kk, dB + _sl * 8192 + 4096);                  \
    }

    const int S = K >> 6;  // K-steps of 64
    KSTAGE_H1(0);
    KSTAGE_H2(0);
    KSTAGE_H1(1);
    KSTAGE_H2(1);
    asm volatile("s_waitcnt vmcnt(6)" ::: "memory");  // slot 0 landed
    __builtin_amdgcn_s_barrier();

    for (int s = 0; s < S; ++s) {
        const int sl = s % 3;
        const unsigned short* as_ = &As[sl][0];
        const unsigned short* bs_ = &Bs[sl][0];
        const bool st = (s + 2) < S;
        bf16x8 a0[4], b0[4], a1[4], b1[4];
        // ---- phase 1: kc = 0
#pragma unroll
        for (int mi = 0; mi < 4; mi++) a0[mi] = *(const bf16x8*)&as_[aoff[0][mi]];
#pragma unroll
        for (int ni = 0; ni < 4; ni++) b0[ni] = *(const bf16x8*)&bs_[boff[0][ni]];
        if (st) KSTAGE_H1(s + 2);
        __builtin_amdgcn_s_barrier();
        asm volatile("s_waitcnt lgkmcnt(0)" ::: "memory");
        __builtin_amdgcn_sched_barrier(0);
        __builtin_amdgcn_s_setprio(1);
#pragma unroll
        for (int mi = 0; mi < 4; mi++)
#pragma unroll
            for (int ni = 0; ni < 4; ni++)
                acc[mi][ni] = MFMA16(a0[mi], b0[ni], acc[mi][ni]);
        __builtin_amdgcn_s_setprio(0);
        __builtin_amdgcn_s_barrier();
        __builtin_amdgcn_sched_barrier(0);
        // ---- phase 2: kc = 1
#pragma unroll
        for (int mi = 0; mi < 4; mi++) a1[mi] = *(const bf16x8*)&as_[aoff[1][mi]];
#pragma unroll
        for (int ni = 0; ni < 4; ni++) b1[ni] = *(const bf16x8*)&bs_[boff[1][ni]];
        if (st) KSTAGE_H2(s + 2);
        __builtin_amdgcn_s_barrier();
        asm volatile("s_waitcnt lgkmcnt(0)" ::: "memory");
        __builtin_amdgcn_sched_barrier(0);
        __builtin_amdgcn_s_setprio(1);
#pragma unroll
        for (int mi = 0; mi < 4; mi++)
#pragma unroll
            for (int ni = 0; ni < 4; ni++)
                acc[mi][ni] = MFMA16(a1[mi], b1[ni], acc[mi][ni]);
        __builtin_amdgcn_s_setprio(0);
        if (st) {
            asm volatile("s_waitcnt vmcnt(6)" ::: "memory");
        } else {
            asm volatile("s_waitcnt vmcnt(0)" ::: "memory");
        }
        __builtin_amdgcn_s_barrier();
        __builtin_amdgcn_sched_barrier(0);
    }
#undef KSTAGE_H1
#undef KSTAGE_H2

#pragma unroll
    for (int ni = 0; ni < 4; ni++) {
        const long col = n0 + wc * 64 + ni * 16 + lr;
        const float bv = bias ? bias[col] : 0.0f;
        const float cscale = (op == 2 && col < 1024) ? QSCALE : 1.0f;
#pragma unroll
        for (int mi = 0; mi < 4; mi++) {
#pragma unroll
            for (int r = 0; r < 4; r++) {
                const long row = m0 + wr * 64 + mi * 16 + quad * 4 + r;
                float v = (acc[mi][ni][r] + bv) * cscale;
                if (resid) v += to_f(resid[row * (long)N + col]);
                if (op == 1) v = fmaxf(v, 0.0f);
                C[row * (long)N + col] = f2b(v);
            }
        }
    }
}

// ---------------------------------------------------------------------------
// Flash attention v7 (transposed-S; K/V LDS-staged XOR-swizzled; NO-MAX
// softmax; in-register P^T redistribution via permlane swaps; ones-MFMA
// denominator). Measured best: 128.7-129.8 us @ 5 blocks/CU. [v9's
// counted-vmcnt ring was NULL: 130.3 at 3 blocks/CU -- the drain is not the
// binding constraint; this structure is at its LDS/trans/VALU floor.]
// ---------------------------------------------------------------------------
__global__ __launch_bounds__(256, 5) void attn_kernel(
    const unsigned short* __restrict__ qkv, const unsigned short* __restrict__ vt,
    unsigned short* __restrict__ o) {
    __shared__ __align__(16) unsigned short Klds[2][64 * 64];  // 16 KB
    __shared__ __align__(16) unsigned short Vlds[2][64 * 64];  // 16 KB
    // Block swizzle: all 32 q-tiles of one (b,h) share l%8 -> same XCD.
    const int l = blockIdx.x;
    const int bh = ((l >> 8) << 3) | (l & 7);
    const int qt = (l >> 3) & 31;
    const int b = bh >> 4, h = bh & 15;
    const int tid = threadIdx.x;
    const int wave = tid >> 6, lane = tid & 63;
    const int quad = lane >> 4, lr = lane & 15;
    const long rowbase = (long)b * 2048;
    const int qb = qt * 64 + wave * 16;

    // Q fragments (B operand; n = query = lr), register-resident
    bf16x8 q0, q1;
    {
        const unsigned short* qrow = qkv + (rowbase + qb + lr) * 3072 + h * 64;
        q0 = *(const bf16x8*)&qrow[quad * 8];
        q1 = *(const bf16x8*)&qrow[32 + quad * 8];
    }

    // all-ones bf16 A-fragment for the denominator MFMA
    bf16x8 ones;
#pragma unroll
    for (int i = 0; i < 8; i++) ones[i] = (short)0x3F80;

    // Staging: wave w stages rows [w*16, w*16+16) of the K and V tiles via
    // 2 gl16 each. Lane: row = base + (lane>>3), dst chunk = lane&7,
    // src chunk = (lane&7) ^ (row&7)  [row&7 == lane>>3 here].
    const int srow = lane >> 3;
    const int sxc = (lane & 7) ^ srow;
    const unsigned short* kp =
        qkv + (rowbase + wave * 16 + srow) * 3072 + 1024 + h * 64 + sxc * 8;
    const unsigned short* vp =
        vt + ((long)bh * 64 + wave * 16 + srow) * 2048 + sxc * 8;
    const long KADV = 64L * 3072;  // next key-tile (rows)
    unsigned short* const kd0 = &Klds[0][wave * 16 * 64];
    unsigned short* const vd0 = &Vlds[0][wave * 16 * 64];

#define STAGE(bf)                                                     \
    {                                                                 \
        gl16(kp, kd0 + (bf)*4096);                                    \
        gl16(kp + 8 * 3072, kd0 + (bf)*4096 + 8 * 64);                \
        gl16(vp, vd0 + (bf)*4096);                                    \
        gl16(vp + 8 * 2048, vd0 + (bf)*4096 + 8 * 64);                \
    }

    f32x4 oacc[4] = {};
    f32x4 dacc = {};  // denominator accumulator (all rows identical)

    // swizzled chunk offsets for A-operand reads (row&7 == lr&7)
    const int x7 = lr & 7;
    const int c00 = (quad ^ x7) * 8;        // kc=0
    const int c01 = ((4 | quad) ^ x7) * 8;  // kc=1

    STAGE(0);
    __syncthreads();

    for (int kt = 0; kt < 32; kt++) {
        const int buf = kt & 1;
        if (kt < 31) {
            kp += KADV;
            vp += 64;
            STAGE(buf ^ 1);
        }
        // S^T = K·Q^T  (A = K tile rows, k-dim = dh)
        const unsigned short* kb = &Klds[buf][0];
        f32x4 s4[4];
#pragma unroll
        for (int nt = 0; nt < 4; nt++) {
            const unsigned short* krow = kb + (nt * 16 + lr) * 64;
            bf16x8 k0 = *(const bf16x8*)&krow[c00];
            bf16x8 k1 = *(const bf16x8*)&krow[c01];
            f32x4 z = {};
            z = MFMA16(k0, q0, z);
            z = MFMA16(k1, q1, z);
            s4[nt] = z;
        }
        // p = exp2(s) unnormalized; pack pairs to bf16 (v_cvt_pk, RNE).
        unsigned pwv[4][2];
#pragma unroll
        for (int nt = 0; nt < 4; nt++) {
            float p0 = exp2f(s4[nt][0]);
            float p1 = exp2f(s4[nt][1]);
            float p2 = exp2f(s4[nt][2]);
            float p3 = exp2f(s4[nt][3]);
            asm("v_cvt_pk_bf16_f32 %0, %1, %2"
                : "=v"(pwv[nt][0]) : "v"(p0), "v"(p1));
            asm("v_cvt_pk_bf16_f32 %0, %1, %2"
                : "=v"(pwv[nt][1]) : "v"(p2), "v"(p3));
        }
        // In-register P^T quad redistribution (permlane swaps).
        unsigned pq[2][4];
#pragma unroll
        for (int kc = 0; kc < 2; kc++)
#pragma unroll
            for (int tl = 0; tl < 2; tl++) {
                u32x2 y = __builtin_amdgcn_permlane32_swap(
                    pwv[2 * kc][tl], pwv[2 * kc + 1][tl], false, false);
                u32x2 z = __builtin_amdgcn_permlane16_swap(y[0], y[1], false, false);
                pq[kc][tl] = z[0];
                pq[kc][2 + tl] = z[1];
            }

        // O^T += V^T·P^T + denominator row-sum on the matrix pipe.
        const unsigned short* vb = &Vlds[buf][0];
#pragma unroll
        for (int kc = 0; kc < 2; kc++) {
            union { unsigned u[4]; bf16x8 h; } pu;
            pu.u[0] = pq[kc][0]; pu.u[1] = pq[kc][1];
            pu.u[2] = pq[kc][2]; pu.u[3] = pq[kc][3];
            const int vc = kc ? c01 : c00;
            dacc = MFMA16(ones, pu.h, dacc);
#pragma unroll
            for (int nt = 0; nt < 4; nt++) {
                bf16x8 va = *(const bf16x8*)&vb[(nt * 16 + lr) * 64 + vc];
                oacc[nt] = MFMA16(va, pu.h, oacc[nt]);
            }
        }
        __syncthreads();  // buf readers done + buf^1 staging drained (vmcnt)
    }

    // dacc rows are identical: dacc[0] = full denominator for query lr.
    const float rinv = 1.0f / dacc[0];

    // O^T C-layout: (e = nt*16+quad*4+r, q = lr) -> packed ushort4 stores
    const long orow = rowbase + qb + lr;
#pragma unroll
    for (int nt = 0; nt < 4; nt++) {
        ushort4 ov = {f2b(oacc[nt][0] * rinv), f2b(oacc[nt][1] * rinv),
                      f2b(oacc[nt][2] * rinv), f2b(oacc[nt][3] * rinv)};
        *(ushort4*)&o[orow * 1024 + h * 64 + nt * 16 + quad * 4] = ov;
    }
#undef STAGE
}

// ---------------------------------------------------------------------------
// LayerNorm over last dim (1024), bf16 in, OT out, fp32 stats/params.
// ---------------------------------------------------------------------------
__device__ __forceinline__ void st4(float* p, float a, float b, float c, float d) {
    float4 v = {a, b, c, d};
    *(float4*)p = v;
}
__device__ __forceinline__ void st4(unsigned short* p, float a, float b, float c,
                                    float d) {
    ushort4 v = {f2b(a), f2b(b), f2b(c), f2b(d)};
    *(ushort4*)p = v;
}

template <typename OT>
__global__ __launch_bounds__(256) void ln_kernel(
    const unsigned short* __restrict__ in, const float* __restrict__ g,
    const float* __restrict__ b, OT* __restrict__ out) {
    __shared__ float red[4];
    const long row = blockIdx.x;
    const int tid = threadIdx.x;
    ushort4 u = *(const ushort4*)&in[row * 1024 + tid * 4];
    float v[4] = {b2f(u.x), b2f(u.y), b2f(u.z), b2f(u.w)};
    float s = v[0] + v[1] + v[2] + v[3];
#pragma unroll
    for (int off = 32; off > 0; off >>= 1) s += __shfl_down(s, off, 64);
    if ((tid & 63) == 0) red[tid >> 6] = s;
    __syncthreads();
    const float mu = (red[0] + red[1] + red[2] + red[3]) * (1.0f / 1024.0f);
    __syncthreads();
    float d[4], sq = 0.f;
#pragma unroll
    for (int i = 0; i < 4; i++) { d[i] = v[i] - mu; sq += d[i] * d[i]; }
#pragma unroll
    for (int off = 32; off > 0; off >>= 1) sq += __shfl_down(sq, off, 64);
    if ((tid & 63) == 0) red[tid >> 6] = sq;
    __syncthreads();
    const float var = (red[0] + red[1] + red[2] + red[3]) * (1.0f / 1024.0f);
    const float rs = rsqrtf(var + 1e-5f);
    float4 gu = *(const float4*)&g[tid * 4];
    float4 bu = *(const float4*)&b[tid * 4];
    st4(&out[row * 1024 + tid * 4], d[0] * rs * gu.x + bu.x,
        d[1] * rs * gu.y + bu.y, d[2] * rs * gu.z + bu.z,
        d[3] * rs * gu.w + bu.w);
}

// ---------------------------------------------------------------------------
extern "C" void kernel_launch(void* const* d_in, const int* in_sizes, int n_in,
                              void* d_out, int out_size, void* d_ws, size_t ws_size,
                              hipStream_t stream) {
    (void)in_sizes; (void)n_in; (void)out_size; (void)ws_size;
    const float* x   = (const float*)d_in[0];
    const float* wq  = (const float*)d_in[1];
    const float* bq  = (const float*)d_in[2];
    const float* wk  = (const float*)d_in[3];
    const float* bk  = (const float*)d_in[4];
    const float* wv  = (const float*)d_in[5];
    const float* bv  = (const float*)d_in[6];
    const float* wo  = (const float*)d_in[7];
    const float* bo  = (const float*)d_in[8];
    const float* g1  = (const float*)d_in[9];
    const float* be1 = (const float*)d_in[10];
    const float* w1  = (const float*)d_in[11];
    const float* b1  = (const float*)d_in[12];
    const float* w2  = (const float*)d_in[13];
    const float* b2  = (const float*)d_in[14];
    const float* g2  = (const float*)d_in[15];
    const float* be2 = (const float*)d_in[16];

    // Workspace (bf16 unless noted), high-water 153 MB.
    char* ws = (char*)d_ws;
    const size_t MB = 1024 * 1024;
    unsigned short* WT_QKV = (unsigned short*)(ws + 0);        // [3072,1024]
    unsigned short* WT_O   = (unsigned short*)(ws + 6 * MB);   // [1024,1024]
    unsigned short* WT_1   = (unsigned short*)(ws + 8 * MB);   // [4096,1024]
    unsigned short* WT_2   = (unsigned short*)(ws + 16 * MB);  // [1024,4096]
    float*          BQKV   = (float*)(ws + 24 * MB);           // [3072]
    unsigned short* XB     = (unsigned short*)(ws + 25 * MB);  // [8192,1024]
    unsigned short* QKV    = (unsigned short*)(ws + 41 * MB);  // [8192,3072]
    unsigned short* O      = (unsigned short*)(ws + 89 * MB);  // [8192,1024]
    unsigned short* R1     = (unsigned short*)(ws + 25 * MB);  // over dead XB
    unsigned short* Y      = (unsigned short*)(ws + 41 * MB);  // over dead QKV
    unsigned short* R2     = (unsigned short*)(ws + 57 * MB);  // over dead QKV
    unsigned short* Hb     = (unsigned short*)(ws + 73 * MB);  // [8192,4096]
    unsigned short* VT     = (unsigned short*)(ws + 137 * MB); // [64,64,2048]
    float*          OUT    = (float*)d_out;

    const dim3 tb(32, 8, 1);
    // Fused preprocessing: 6 transposes + bias concat + x f2b in ONE launch.
    prep_kernel<<<dim3(16396), tb, 0, stream>>>(
        wq, wk, wv, wo, w1, w2, bq, bk, bv, x,
        WT_QKV, WT_O, WT_1, WT_2, BQKV, XB);

    // QKV projection: BM=256 BN=128, grid 24x32 = 768 blocks (3 full rounds)
    gemmK64<0, unsigned short><<<dim3(24, 32), 512, 0, stream>>>(
        XB, WT_QKV, QKV, BQKV, (const unsigned short*)nullptr, 8192, 3072, 1024, 2);
    // V^T per head -> VT
    transpose_v<<<dim3(64, 2, 64), tb, 0, stream>>>(QKV, VT);
    // Flash attention -> O
    attn_kernel<<<dim3(2048), 256, 0, stream>>>(QKV, VT, O);
    // Out-proj + bo + residual x(fp32) -> R1: grid 8x32 = 256 (1 full round)
    gemmK64<1, float><<<dim3(8, 32), 512, 0, stream>>>(
        O, WT_O, R1, bo, x, 8192, 1024, 1024, 0);
    // LN1 -> Y
    ln_kernel<unsigned short><<<dim3(8192), 256, 0, stream>>>(R1, g1, be1, Y);
    // FF1 + b1 + ReLU -> Hb: 256x256 tiles, grid 16x32 = 512 (2 full rounds)
    gemm256<unsigned short><<<dim3(16, 32), 512, 0, stream>>>(
        Y, WT_1, Hb, b1, (const unsigned short*)nullptr, 8192, 4096, 1024, 1);
    // FF2 + b2 + residual Y -> R2: grid 8x32 = 256 (1 full round), K=4096
    gemmK64<2, unsigned short><<<dim3(8, 32), 512, 0, stream>>>(
        Hb, WT_2, R2, b2, Y, 8192, 1024, 4096, 0);
    // LN2 -> out (fp32)
    ln_kernel<float><<<dim3(8192), 256, 0, stream>>>(R2, g2, be2, OUT);
}